// Round 3
// baseline (275.077 us; speedup 1.0000x reference)
//
#include <hip/hip_runtime.h>
#include <hip/hip_bf16.h>

#define E_DIM 1024
#define NHEAD 16
#define HDIM  64
#define BATCH 4
#define SEQ   2048
#define RQKV  (3 * E_DIM)

typedef __attribute__((ext_vector_type(8))) short bf16x8;
typedef __attribute__((ext_vector_type(4))) float f32x4;
typedef __attribute__((ext_vector_type(16))) float f32x16;

static __device__ __forceinline__ unsigned short bits_of(__hip_bfloat16 h) {
    return *reinterpret_cast<unsigned short*>(&h);
}

static __device__ __forceinline__ void gload_lds16(const void* g, void* l) {
    __builtin_amdgcn_global_load_lds(
        (__attribute__((address_space(1))) void*)g,
        (__attribute__((address_space(3))) void*)l, 16, 0, 0);
}

// ---------------- cast fp32 -> bf16, 4 elems/thread ----------------
__global__ void cast_kernel(const float* __restrict__ in,
                            __hip_bfloat16* __restrict__ out, int n4) {
    int i = blockIdx.x * blockDim.x + threadIdx.x;
    if (i < n4) {
        float4 v = reinterpret_cast<const float4*>(in)[i];
        ushort4 u;
        u.x = bits_of(__float2bfloat16(v.x));
        u.y = bits_of(__float2bfloat16(v.y));
        u.z = bits_of(__float2bfloat16(v.z));
        u.w = bits_of(__float2bfloat16(v.w));
        reinterpret_cast<ushort4*>(out)[i] = u;
    }
}

// fused 4-weight cast: blockIdx.y selects the weight
__global__ void cast4_kernel(const float* __restrict__ w0, const float* __restrict__ w1,
                             const float* __restrict__ w2, const float* __restrict__ w3,
                             __hip_bfloat16* __restrict__ o0, __hip_bfloat16* __restrict__ o1,
                             __hip_bfloat16* __restrict__ o2, __hip_bfloat16* __restrict__ o3,
                             int n4) {
    const float* in; __hip_bfloat16* out;
    switch (blockIdx.y) {
        case 0:  in = w0; out = o0; break;
        case 1:  in = w1; out = o1; break;
        case 2:  in = w2; out = o2; break;
        default: in = w3; out = o3; break;
    }
    int i = blockIdx.x * blockDim.x + threadIdx.x;
    if (i < n4) {
        float4 v = reinterpret_cast<const float4*>(in)[i];
        ushort4 u;
        u.x = bits_of(__float2bfloat16(v.x));
        u.y = bits_of(__float2bfloat16(v.y));
        u.z = bits_of(__float2bfloat16(v.z));
        u.w = bits_of(__float2bfloat16(v.w));
        reinterpret_cast<ushort4*>(out)[i] = u;
    }
}

// ---------------- GEMM (m97 structure): C[m][n] = sum_k A[m][k] * Bw[n][k] ----
// 128x128 tile, BK=32, 4 waves, global_load_lds width=16, linear LDS,
// XCD-bijective block swizzle (requires nwg % 8 == 0).
template<int OUT_BF16>
__global__ __launch_bounds__(256) void gemm_bt(
    const __hip_bfloat16* __restrict__ A,
    const __hip_bfloat16* __restrict__ Bw,
    void* __restrict__ Cv, int M, int N, int K) {
    __shared__ __align__(16) __hip_bfloat16 As[128][32];
    __shared__ __align__(16) __hip_bfloat16 Bs[128][32];

    const int nbx = gridDim.x;
    const int lin = blockIdx.y * nbx + blockIdx.x;
    const int cpx = (nbx * gridDim.y) >> 3;
    const int swz = (lin & 7) * cpx + (lin >> 3);
    const int mBase = (swz / nbx) * 128, nBase = (swz % nbx) * 128;

    const int t = threadIdx.x;
    const int lane = t & 63, w = t >> 6;
    const int wr = (w >> 1) * 64, wc = (w & 1) * 64;
    const int lr = lane & 15, lk = (lane >> 4) * 8;
    const int sr = t >> 2, sc = (t & 3) * 8;        // staging row / col
    const int wbase = w * 1024;                     // LDS byte base of wave

    f32x4 acc[4][4];
#pragma unroll
    for (int i = 0; i < 4; ++i)
#pragma unroll
        for (int j = 0; j < 4; ++j) acc[i][j] = (f32x4){0.f, 0.f, 0.f, 0.f};

    for (int kt = 0; kt < K; kt += 32) {
        __syncthreads();
#pragma unroll
        for (int it = 0; it < 2; ++it) {
            gload_lds16(A + (size_t)(mBase + sr + it * 64) * K + kt + sc,
                        (char*)&As[0][0] + wbase + it * 4096);
            gload_lds16(Bw + (size_t)(nBase + sr + it * 64) * K + kt + sc,
                        (char*)&Bs[0][0] + wbase + it * 4096);
        }
        __syncthreads();
        bf16x8 af[4], bfr[4];
#pragma unroll
        for (int i = 0; i < 4; ++i) {
            af[i]  = *reinterpret_cast<const bf16x8*>(&As[wr + i * 16 + lr][lk]);
            bfr[i] = *reinterpret_cast<const bf16x8*>(&Bs[wc + i * 16 + lr][lk]);
        }
        __builtin_amdgcn_s_setprio(1);
#pragma unroll
        for (int i = 0; i < 4; ++i)
#pragma unroll
            for (int j = 0; j < 4; ++j)
                acc[i][j] = __builtin_amdgcn_mfma_f32_16x16x32_bf16(
                    af[i], bfr[j], acc[i][j], 0, 0, 0);
        __builtin_amdgcn_s_setprio(0);
    }

#pragma unroll
    for (int i = 0; i < 4; ++i)
#pragma unroll
        for (int j = 0; j < 4; ++j)
#pragma unroll
            for (int v = 0; v < 4; ++v) {
                const int row = mBase + wr + i * 16 + (lane >> 4) * 4 + v;
                const int col = nBase + wc + j * 16 + lr;
                if (OUT_BF16)
                    ((__hip_bfloat16*)Cv)[(size_t)row * N + col] =
                        __float2bfloat16(acc[i][j][v]);
                else
                    ((float*)Cv)[(size_t)row * N + col] = acc[i][j][v];
            }
}

// ---------------- flash attention, 4 waves x 32 q-rows, KVBLK=64 ----------------
// Double-buffered LDS, ONE barrier per tile: prefetch (K gload_lds + V reg
// loads) issued post-barrier so they overlap tile-kt compute. Swapped QK^T,
// in-register softmax with defer-max, P via pack+permlane32_swap, setprio(1)
// around MFMA clusters. Heaviest causal blocks scheduled first.
__global__ __launch_bounds__(256) void attn_kernel(
    const __hip_bfloat16* __restrict__ QKV,   // [B*S][3E], Q|K|V blocks
    __hip_bfloat16* __restrict__ O) {         // [B*S][E]
    __shared__ __align__(16) __hip_bfloat16 Kl[2][64][64];
    __shared__ __align__(16) __hip_bfloat16 Vt[2][64][64];

    const int t = threadIdx.x, w = t >> 6, lane = t & 63;
    const int lq = lane & 31, hi = lane >> 5;
    const int qb = (gridDim.x - 1) - blockIdx.x;   // heavy blocks first
    const int qb0 = qb * 128;
    const int h = blockIdx.y, b = blockIdx.z;

    const size_t rb = (size_t)b * SEQ;
    const __hip_bfloat16* Qg = QKV + rb * RQKV + h * HDIM;
    const __hip_bfloat16* Kg = QKV + rb * RQKV + E_DIM + h * HDIM;
    const __hip_bfloat16* Vg = QKV + rb * RQKV + 2 * E_DIM + h * HDIM;

    const int qg = qb0 + w * 32 + lq;

    bf16x8 aq[4];
#pragma unroll
    for (int d0 = 0; d0 < 4; ++d0)
        aq[d0] = *reinterpret_cast<const bf16x8*>(
            Qg + (size_t)qg * RQKV + d0 * 16 + hi * 8);

    f32x16 oa[2];
#pragma unroll
    for (int m = 0; m < 2; ++m)
#pragma unroll
        for (int r = 0; r < 16; ++r) oa[m][r] = 0.f;
    float m_run = -1e30f, l_run = 0.f;

    const int vkp = t & 31, vd0 = (t >> 5) * 8;
    const float SCL2 = 0.04508422f;               // (1/32) * log2(e)

    const int NT = qb * 2 + 2;

    // ---- prologue: stage tile 0 ----
    bf16x8 va, vb;
    {
#pragma unroll
        for (int i = 0; i < 2; ++i) {
            const int r = w * 16 + i * 8 + (lane >> 3);
            const char* src = (const char*)(Kg + (size_t)r * RQKV) +
                              (((lane & 7) * 16) ^ ((lane >> 3) << 4));
            gload_lds16(src, (char*)&Kl[0][w * 16 + i * 8][0]);
        }
        const __hip_bfloat16* vp = Vg + (size_t)(2 * vkp) * RQKV + vd0;
        va = *reinterpret_cast<const bf16x8*>(vp);
        vb = *reinterpret_cast<const bf16x8*>(vp + RQKV);
    }

    int buf = 0;
    for (int kt = 0; kt < NT; ++kt) {
        const int k0 = kt * 64;
        // write V regs (tile kt) into Vt[buf], transposed+swizzled
        {
            char* vbase = (char*)&Vt[buf][0][0];
#pragma unroll
            for (int j = 0; j < 8; ++j) {
                const int d = vd0 + j;
                const unsigned wbits =
                    ((unsigned)(unsigned short)vb[j] << 16) |
                    (unsigned short)va[j];
                *reinterpret_cast<unsigned*>(
                    vbase + d * 128 + ((vkp * 4) ^ ((d & 7) << 4))) = wbits;
            }
        }
        __syncthreads();   // drains K gloads (vmcnt) + V writes (lgkm), syncs WAR

        // ---- prefetch tile kt+1 into buf^1 (flies during compute below) ----
        if (kt + 1 < NT) {
            const int k0n = k0 + 64;
#pragma unroll
            for (int i = 0; i < 2; ++i) {
                const int r = w * 16 + i * 8 + (lane >> 3);
                const char* src = (const char*)(Kg + (size_t)(k0n + r) * RQKV) +
                                  (((lane & 7) * 16) ^ ((lane >> 3) << 4));
                gload_lds16(src, (char*)&Kl[buf ^ 1][w * 16 + i * 8][0]);
            }
            const __hip_bfloat16* vp = Vg + (size_t)(k0n + 2 * vkp) * RQKV + vd0;
            va = *reinterpret_cast<const bf16x8*>(vp);
            vb = *reinterpret_cast<const bf16x8*>(vp + RQKV);
        }

        if (k0 <= qb0 + w * 32 + 31) {   // wave has >=1 valid key in this tile
            // ---- QK^T (swapped): S^T, lane owns q = lane&31 ----
            f32x16 sc2[2];
            const char* klbase = (const char*)&Kl[buf][0][0];
#pragma unroll
            for (int tt = 0; tt < 2; ++tt) {
#pragma unroll
                for (int r = 0; r < 16; ++r) sc2[tt][r] = 0.f;
                const int kr = tt * 32 + lq;
                const char* kbase = klbase + kr * 128;
                const int swz = (kr & 7) << 4;
                __builtin_amdgcn_s_setprio(1);
#pragma unroll
                for (int d0 = 0; d0 < 4; ++d0) {
                    bf16x8 ak = *reinterpret_cast<const bf16x8*>(
                        kbase + ((d0 * 32 + hi * 16) ^ swz));
                    sc2[tt] = __builtin_amdgcn_mfma_f32_32x32x16_bf16(
                        ak, aq[d0], sc2[tt], 0, 0, 0);
                }
                __builtin_amdgcn_s_setprio(0);
            }
            // ---- causal mask (skipped when tile fully below diagonal) ----
            if (k0 + 63 > qb0 + w * 32) {
#pragma unroll
                for (int tt = 0; tt < 2; ++tt)
#pragma unroll
                    for (int r = 0; r < 16; ++r) {
                        const int kgl = k0 + tt * 32 +
                                        (r & 3) + 8 * (r >> 2) + 4 * hi;
                        if (kgl > qg) sc2[tt][r] = -1e30f;
                    }
            }
            // ---- online softmax, defer-max (T13) ----
            float mt = sc2[0][0];
#pragma unroll
            for (int tt = 0; tt < 2; ++tt)
#pragma unroll
                for (int r = 0; r < 16; ++r) mt = fmaxf(mt, sc2[tt][r]);
            mt = fmaxf(mt, __shfl_xor(mt, 32));
            if (!__all(mt <= m_run + 177.445f)) {   // (mt-m_run)*SCL2 > 8 somewhere
                const float mn = fmaxf(m_run, mt);
                const float corr = exp2f((m_run - mn) * SCL2);
                l_run *= corr;
                oa[0] *= corr;
                oa[1] *= corr;
                m_run = mn;
            }
            const float nb = -m_run * SCL2;
            float rsum = 0.f;
#pragma unroll
            for (int tt = 0; tt < 2; ++tt)
#pragma unroll
                for (int r = 0; r < 16; ++r) {
                    const float p = exp2f(__builtin_fmaf(sc2[tt][r], SCL2, nb));
                    sc2[tt][r] = p;
                    rsum += p;
                }
            rsum += __shfl_xor(rsum, 32);
            l_run += rsum;

            // ---- P -> bf16 B-frags via pack + permlane32_swap; PV ----
#pragma unroll
            for (int tt = 0; tt < 2; ++tt)
#pragma unroll
                for (int sl = 0; sl < 2; ++sl) {
                    const int rbs = sl * 8;
                    const unsigned wA =
                        ((unsigned)bits_of(__float2bfloat16(sc2[tt][rbs + 1])) << 16) |
                        bits_of(__float2bfloat16(sc2[tt][rbs + 0]));
                    const unsigned wB =
                        ((unsigned)bits_of(__float2bfloat16(sc2[tt][rbs + 3])) << 16) |
                        bits_of(__float2bfloat16(sc2[tt][rbs + 2]));
                    const unsigned wC =
                        ((unsigned)bits_of(__float2bfloat16(sc2[tt][rbs + 5])) << 16) |
                        bits_of(__float2bfloat16(sc2[tt][rbs + 4]));
                    const unsigned wD =
                        ((unsigned)bits_of(__float2bfloat16(sc2[tt][rbs + 7])) << 16) |
                        bits_of(__float2bfloat16(sc2[tt][rbs + 6]));
                    const auto pA = __builtin_amdgcn_permlane32_swap(wA, wC, false, false);
                    const auto pB = __builtin_amdgcn_permlane32_swap(wB, wD, false, false);
                    union { unsigned u[4]; bf16x8 v; } pf;
                    pf.u[0] = pA[0]; pf.u[1] = pB[0];
                    pf.u[2] = pA[1]; pf.u[3] = pB[1];
                    const int ks = tt * 2 + sl;
                    const char* vtbase = (const char*)&Vt[buf][0][0];
                    __builtin_amdgcn_s_setprio(1);
#pragma unroll
                    for (int m = 0; m < 2; ++m) {
                        const int dr = m * 32 + lq;
                        bf16x8 av = *reinterpret_cast<const bf16x8*>(
                            vtbase + dr * 128 +
                            ((ks * 32 + hi * 16) ^ ((dr & 7) << 4)));
                        oa[m] = __builtin_amdgcn_mfma_f32_32x32x16_bf16(
                            av, pf.v, oa[m], 0, 0, 0);
                    }
                    __builtin_amdgcn_s_setprio(0);
                }
        }
        buf ^= 1;
    }

    // ---- epilogue ----
    const float inv = 1.f / l_run;
    __hip_bfloat16* Orow = O + (rb + qg) * E_DIM + h * HDIM;
#pragma unroll
    for (int m = 0; m < 2; ++m)
#pragma unroll
        for (int q4 = 0; q4 < 4; ++q4) {
            ushort4 pk;
            pk.x = bits_of(__float2bfloat16(oa[m][q4 * 4 + 0] * inv));
            pk.y = bits_of(__float2bfloat16(oa[m][q4 * 4 + 1] * inv));
            pk.z = bits_of(__float2bfloat16(oa[m][q4 * 4 + 2] * inv));
            pk.w = bits_of(__float2bfloat16(oa[m][q4 * 4 + 3] * inv));
            *reinterpret_cast<ushort4*>(Orow + m * 32 + q4 * 8 + 4 * hi) = pk;
        }
}

// ---------------- launch ----------------
extern "C" void kernel_launch(void* const* d_in, const int* in_sizes, int n_in,
                              void* d_out, int out_size, void* d_ws, size_t ws_size,
                              hipStream_t stream) {
    const float* x  = (const float*)d_in[0];
    const float* wq = (const float*)d_in[1];
    const float* wk = (const float*)d_in[2];
    const float* wv = (const float*)d_in[3];
    const float* wo = (const float*)d_in[4];

    const size_t SZ_X = (size_t)BATCH * SEQ * E_DIM;   // 8388608
    const size_t SZ_W = (size_t)E_DIM * E_DIM;         // 1048576

    char* p = (char*)d_ws;
    __hip_bfloat16* xb    = (__hip_bfloat16*)p; p += SZ_X * 2;
    __hip_bfloat16* wqkvb = (__hip_bfloat16*)p; p += 3 * SZ_W * 2;   // [3E][E]
    __hip_bfloat16* wob   = (__hip_bfloat16*)p; p += SZ_W * 2;
    __hip_bfloat16* QKVb  = (__hip_bfloat16*)p; p += SZ_X * 3 * 2;   // [M][3E]
    __hip_bfloat16* attb  = (__hip_bfloat16*)p; p += SZ_X * 2;

    cast_kernel<<<(int)(SZ_X / 4 / 256), 256, 0, stream>>>(x, xb, (int)(SZ_X / 4));
    cast4_kernel<<<dim3((unsigned)(SZ_W / 4 / 256), 4), 256, 0, stream>>>(
        wq, wk, wv, wo, wqkvb, wqkvb + SZ_W, wqkvb + 2 * SZ_W, wob,
        (int)(SZ_W / 4));

    const int M = BATCH * SEQ;  // 8192
    gemm_bt<1><<<dim3(RQKV / 128, M / 128), 256, 0, stream>>>(
        xb, wqkvb, QKVb, M, RQKV, E_DIM);

    attn_kernel<<<dim3(SEQ / 128, NHEAD, BATCH), 256, 0, stream>>>(QKVb, attb);

    gemm_bt<0><<<dim3(E_DIM / 128, M / 128), 256, 0, stream>>>(
        attb, wob, d_out, M, E_DIM, E_DIM);
}

// Round 4
// 205.161 us; speedup vs baseline: 1.3408x; 1.3408x over previous
//
#include <hip/hip_runtime.h>
#include <hip/hip_bf16.h>

#define E_DIM 1024
#define NHEAD 16
#define HDIM  64
#define BATCH 4
#define SEQ   2048
#define RQKV  (3 * E_DIM)

typedef __attribute__((ext_vector_type(8))) short bf16x8;
typedef __attribute__((ext_vector_type(4))) float f32x4;
typedef __attribute__((ext_vector_type(16))) float f32x16;

static __device__ __forceinline__ unsigned short bits_of(__hip_bfloat16 h) {
    return *reinterpret_cast<unsigned short*>(&h);
}

static __device__ __forceinline__ void gload_lds16(const void* g, void* l) {
    __builtin_amdgcn_global_load_lds(
        (__attribute__((address_space(1))) void*)g,
        (__attribute__((address_space(3))) void*)l, 16, 0, 0);
}

// ---------------- cast fp32 -> bf16, 4 elems/thread ----------------
__global__ void cast_kernel(const float* __restrict__ in,
                            __hip_bfloat16* __restrict__ out, int n4) {
    int i = blockIdx.x * blockDim.x + threadIdx.x;
    if (i < n4) {
        float4 v = reinterpret_cast<const float4*>(in)[i];
        ushort4 u;
        u.x = bits_of(__float2bfloat16(v.x));
        u.y = bits_of(__float2bfloat16(v.y));
        u.z = bits_of(__float2bfloat16(v.z));
        u.w = bits_of(__float2bfloat16(v.w));
        reinterpret_cast<ushort4*>(out)[i] = u;
    }
}

// fused 4-weight cast: blockIdx.y selects the weight
__global__ void cast4_kernel(const float* __restrict__ w0, const float* __restrict__ w1,
                             const float* __restrict__ w2, const float* __restrict__ w3,
                             __hip_bfloat16* __restrict__ o0, __hip_bfloat16* __restrict__ o1,
                             __hip_bfloat16* __restrict__ o2, __hip_bfloat16* __restrict__ o3,
                             int n4) {
    const float* in; __hip_bfloat16* out;
    switch (blockIdx.y) {
        case 0:  in = w0; out = o0; break;
        case 1:  in = w1; out = o1; break;
        case 2:  in = w2; out = o2; break;
        default: in = w3; out = o3; break;
    }
    int i = blockIdx.x * blockDim.x + threadIdx.x;
    if (i < n4) {
        float4 v = reinterpret_cast<const float4*>(in)[i];
        ushort4 u;
        u.x = bits_of(__float2bfloat16(v.x));
        u.y = bits_of(__float2bfloat16(v.y));
        u.z = bits_of(__float2bfloat16(v.z));
        u.w = bits_of(__float2bfloat16(v.w));
        reinterpret_cast<ushort4*>(out)[i] = u;
    }
}

// ---------------- GEMM (m97 structure): C[m][n] = sum_k A[m][k] * Bw[n][k] ----
// 128x128 tile, BK=32, 4 waves, global_load_lds width=16, linear LDS,
// XCD-bijective block swizzle (requires nwg % 8 == 0).
template<int OUT_BF16>
__global__ __launch_bounds__(256) void gemm_bt(
    const __hip_bfloat16* __restrict__ A,
    const __hip_bfloat16* __restrict__ Bw,
    void* __restrict__ Cv, int M, int N, int K) {
    __shared__ __align__(16) __hip_bfloat16 As[128][32];
    __shared__ __align__(16) __hip_bfloat16 Bs[128][32];

    const int nbx = gridDim.x;
    const int lin = blockIdx.y * nbx + blockIdx.x;
    const int cpx = (nbx * gridDim.y) >> 3;
    const int swz = (lin & 7) * cpx + (lin >> 3);
    const int mBase = (swz / nbx) * 128, nBase = (swz % nbx) * 128;

    const int t = threadIdx.x;
    const int lane = t & 63, w = t >> 6;
    const int wr = (w >> 1) * 64, wc = (w & 1) * 64;
    const int lr = lane & 15, lk = (lane >> 4) * 8;
    const int sr = t >> 2, sc = (t & 3) * 8;        // staging row / col
    const int wbase = w * 1024;                     // LDS byte base of wave

    f32x4 acc[4][4];
#pragma unroll
    for (int i = 0; i < 4; ++i)
#pragma unroll
        for (int j = 0; j < 4; ++j) acc[i][j] = (f32x4){0.f, 0.f, 0.f, 0.f};

    for (int kt = 0; kt < K; kt += 32) {
        __syncthreads();
#pragma unroll
        for (int it = 0; it < 2; ++it) {
            gload_lds16(A + (size_t)(mBase + sr + it * 64) * K + kt + sc,
                        (char*)&As[0][0] + wbase + it * 4096);
            gload_lds16(Bw + (size_t)(nBase + sr + it * 64) * K + kt + sc,
                        (char*)&Bs[0][0] + wbase + it * 4096);
        }
        __syncthreads();
        bf16x8 af[4], bfr[4];
#pragma unroll
        for (int i = 0; i < 4; ++i) {
            af[i]  = *reinterpret_cast<const bf16x8*>(&As[wr + i * 16 + lr][lk]);
            bfr[i] = *reinterpret_cast<const bf16x8*>(&Bs[wc + i * 16 + lr][lk]);
        }
#pragma unroll
        for (int i = 0; i < 4; ++i)
#pragma unroll
            for (int j = 0; j < 4; ++j)
                acc[i][j] = __builtin_amdgcn_mfma_f32_16x16x32_bf16(
                    af[i], bfr[j], acc[i][j], 0, 0, 0);
    }

#pragma unroll
    for (int i = 0; i < 4; ++i)
#pragma unroll
        for (int j = 0; j < 4; ++j)
#pragma unroll
            for (int v = 0; v < 4; ++v) {
                const int row = mBase + wr + i * 16 + (lane >> 4) * 4 + v;
                const int col = nBase + wc + j * 16 + lr;
                if (OUT_BF16)
                    ((__hip_bfloat16*)Cv)[(size_t)row * N + col] =
                        __float2bfloat16(acc[i][j][v]);
                else
                    ((float*)Cv)[(size_t)row * N + col] = acc[i][j][v];
            }
}

// ---------------- flash attention, paired causal blocks ----------------
// Round-2 structure (single-buffer, 2 barriers/tile). Block x handles q-tiles
// qb=x (2x+2 key-tiles) AND qb=15-x (32-2x key-tiles) -> uniform 34 tiles per
// block, eliminating the 16:1 causal work imbalance. Grid (8, H, B).
__global__ __launch_bounds__(256) void attn_kernel(
    const __hip_bfloat16* __restrict__ QKV,   // [B*S][3E], Q|K|V blocks
    __hip_bfloat16* __restrict__ O) {         // [B*S][E]
    __shared__ __align__(16) __hip_bfloat16 Kl[64][64];
    __shared__ __align__(16) __hip_bfloat16 Vt[64][64];

    const int t = threadIdx.x, w = t >> 6, lane = t & 63;
    const int lq = lane & 31, hi = lane >> 5;
    const int h = blockIdx.y, b = blockIdx.z;

    const size_t rb = (size_t)b * SEQ;
    const __hip_bfloat16* Qg = QKV + rb * RQKV + h * HDIM;
    const __hip_bfloat16* Kg = QKV + rb * RQKV + E_DIM + h * HDIM;
    const __hip_bfloat16* Vg = QKV + rb * RQKV + 2 * E_DIM + h * HDIM;

    const int kst_row  = w * 16 + (lane >> 3);
    const int kst_slot = lane & 7;
    const int vkp = t & 31, vd0 = (t >> 5) * 8;
    const float SC = 0.03125f;                 // 1/sqrt(E) = 1/32

#pragma unroll 1
    for (int ph = 0; ph < 2; ++ph) {
        const int qb  = (ph == 0) ? (int)blockIdx.x : 15 - (int)blockIdx.x;
        const int qb0 = qb * 128;
        const int qg  = qb0 + w * 32 + lq;

        bf16x8 aq[4];
#pragma unroll
        for (int d0 = 0; d0 < 4; ++d0)
            aq[d0] = *reinterpret_cast<const bf16x8*>(
                Qg + (size_t)qg * RQKV + d0 * 16 + hi * 8);

        f32x16 oa[2];
#pragma unroll
        for (int m = 0; m < 2; ++m)
#pragma unroll
            for (int r = 0; r < 16; ++r) oa[m][r] = 0.f;
        float m_run = -1e30f, l_run = 0.f;

        const int NT = qb * 2 + 2;
        for (int kt = 0; kt < NT; ++kt) {
            const int k0 = kt * 64;
            __syncthreads();   // previous tile's (or phase's) LDS reads done

            // --- stage K[64][64] swizzled via pre-swizzled global src ---
#pragma unroll
            for (int i = 0; i < 2; ++i) {
                const int r = kst_row + i * 8;
                const char* src = (const char*)(Kg + (size_t)(k0 + r) * RQKV) +
                                  ((kst_slot * 16) ^ ((r & 7) << 4));
                gload_lds16(src, &Kl[w * 16 + i * 8][0]);
            }
            // --- stage V transposed: Vt[d][k], packed b32 writes ---
            {
                const __hip_bfloat16* vp = Vg + (size_t)(k0 + 2 * vkp) * RQKV + vd0;
                bf16x8 va = *reinterpret_cast<const bf16x8*>(vp);
                bf16x8 vb = *reinterpret_cast<const bf16x8*>(vp + RQKV);
#pragma unroll
                for (int j = 0; j < 8; ++j) {
                    const int d = vd0 + j;
                    const unsigned wbits =
                        ((unsigned)(unsigned short)vb[j] << 16) |
                        (unsigned short)va[j];
                    *reinterpret_cast<unsigned*>(
                        reinterpret_cast<char*>(&Vt[0][0]) + d * 128 +
                        ((vkp * 4) ^ ((d & 7) << 4))) = wbits;
                }
            }
            __syncthreads();

            if (k0 <= qb0 + w * 32 + 31) {
                // --- QK^T (swapped): S^T, lane owns q = lane&31 ---
                f32x16 sc2[2];
#pragma unroll
                for (int tt = 0; tt < 2; ++tt) {
#pragma unroll
                    for (int r = 0; r < 16; ++r) sc2[tt][r] = 0.f;
                    const int kr = tt * 32 + lq;
                    const char* kbase =
                        reinterpret_cast<const char*>(&Kl[0][0]) + kr * 128;
                    const int swz = (kr & 7) << 4;
#pragma unroll
                    for (int d0 = 0; d0 < 4; ++d0) {
                        bf16x8 ak = *reinterpret_cast<const bf16x8*>(
                            kbase + ((d0 * 32 + hi * 16) ^ swz));
                        sc2[tt] = __builtin_amdgcn_mfma_f32_32x32x16_bf16(
                            ak, aq[d0], sc2[tt], 0, 0, 0);
                    }
                }
                // --- causal mask (skipped when tile fully valid) ---
                if (k0 + 63 > qb0 + w * 32) {
#pragma unroll
                    for (int tt = 0; tt < 2; ++tt)
#pragma unroll
                        for (int r = 0; r < 16; ++r) {
                            const int kgl = k0 + tt * 32 +
                                            (r & 3) + 8 * (r >> 2) + 4 * hi;
                            if (kgl > qg) sc2[tt][r] = -1e30f;
                        }
                }
                // --- online softmax ---
                float mt = sc2[0][0];
#pragma unroll
                for (int tt = 0; tt < 2; ++tt)
#pragma unroll
                    for (int r = 0; r < 16; ++r) mt = fmaxf(mt, sc2[tt][r]);
                mt = fmaxf(mt, __shfl_xor(mt, 32));
                const float mn = fmaxf(m_run, mt);
                const float corr = __expf((m_run - mn) * SC);
                float rsum = 0.f;
#pragma unroll
                for (int tt = 0; tt < 2; ++tt)
#pragma unroll
                    for (int r = 0; r < 16; ++r) {
                        const float p = __expf((sc2[tt][r] - mn) * SC);
                        sc2[tt][r] = p;
                        rsum += p;
                    }
                rsum += __shfl_xor(rsum, 32);
                l_run = l_run * corr + rsum;
                m_run = mn;
                oa[0] *= corr;
                oa[1] *= corr;

                // --- P -> bf16 B-frags via pack + permlane32_swap; PV ---
#pragma unroll
                for (int tt = 0; tt < 2; ++tt)
#pragma unroll
                    for (int sl = 0; sl < 2; ++sl) {
                        const int rbs = sl * 8;
                        const unsigned wA =
                            ((unsigned)bits_of(__float2bfloat16(sc2[tt][rbs + 1])) << 16) |
                            bits_of(__float2bfloat16(sc2[tt][rbs + 0]));
                        const unsigned wB =
                            ((unsigned)bits_of(__float2bfloat16(sc2[tt][rbs + 3])) << 16) |
                            bits_of(__float2bfloat16(sc2[tt][rbs + 2]));
                        const unsigned wC =
                            ((unsigned)bits_of(__float2bfloat16(sc2[tt][rbs + 5])) << 16) |
                            bits_of(__float2bfloat16(sc2[tt][rbs + 4]));
                        const unsigned wD =
                            ((unsigned)bits_of(__float2bfloat16(sc2[tt][rbs + 7])) << 16) |
                            bits_of(__float2bfloat16(sc2[tt][rbs + 6]));
                        const auto pA = __builtin_amdgcn_permlane32_swap(wA, wC, false, false);
                        const auto pB = __builtin_amdgcn_permlane32_swap(wB, wD, false, false);
                        union { unsigned u[4]; bf16x8 v; } pf;
                        pf.u[0] = pA[0]; pf.u[1] = pB[0];
                        pf.u[2] = pA[1]; pf.u[3] = pB[1];
                        const int ks = tt * 2 + sl;
#pragma unroll
                        for (int m = 0; m < 2; ++m) {
                            const int dr = m * 32 + lq;
                            bf16x8 av = *reinterpret_cast<const bf16x8*>(
                                reinterpret_cast<const char*>(&Vt[0][0]) + dr * 128 +
                                ((ks * 32 + hi * 16) ^ ((dr & 7) << 4)));
                            oa[m] = __builtin_amdgcn_mfma_f32_32x32x16_bf16(
                                av, pf.v, oa[m], 0, 0, 0);
                        }
                    }
            }
        }

        // --- epilogue for this phase ---
        const float inv = 1.f / l_run;
        __hip_bfloat16* Orow = O + (rb + qg) * E_DIM + h * HDIM;
#pragma unroll
        for (int m = 0; m < 2; ++m)
#pragma unroll
            for (int q4 = 0; q4 < 4; ++q4) {
                ushort4 pk;
                pk.x = bits_of(__float2bfloat16(oa[m][q4 * 4 + 0] * inv));
                pk.y = bits_of(__float2bfloat16(oa[m][q4 * 4 + 1] * inv));
                pk.z = bits_of(__float2bfloat16(oa[m][q4 * 4 + 2] * inv));
                pk.w = bits_of(__float2bfloat16(oa[m][q4 * 4 + 3] * inv));
                *reinterpret_cast<ushort4*>(Orow + m * 32 + q4 * 8 + 4 * hi) = pk;
            }
    }
}

// ---------------- launch ----------------
extern "C" void kernel_launch(void* const* d_in, const int* in_sizes, int n_in,
                              void* d_out, int out_size, void* d_ws, size_t ws_size,
                              hipStream_t stream) {
    const float* x  = (const float*)d_in[0];
    const float* wq = (const float*)d_in[1];
    const float* wk = (const float*)d_in[2];
    const float* wv = (const float*)d_in[3];
    const float* wo = (const float*)d_in[4];

    const size_t SZ_X = (size_t)BATCH * SEQ * E_DIM;   // 8388608
    const size_t SZ_W = (size_t)E_DIM * E_DIM;         // 1048576

    char* p = (char*)d_ws;
    __hip_bfloat16* xb    = (__hip_bfloat16*)p; p += SZ_X * 2;
    __hip_bfloat16* wqkvb = (__hip_bfloat16*)p; p += 3 * SZ_W * 2;   // [3E][E]
    __hip_bfloat16* wob   = (__hip_bfloat16*)p; p += SZ_W * 2;
    __hip_bfloat16* QKVb  = (__hip_bfloat16*)p; p += SZ_X * 3 * 2;   // [M][3E]
    __hip_bfloat16* attb  = (__hip_bfloat16*)p; p += SZ_X * 2;

    cast_kernel<<<(int)(SZ_X / 4 / 256), 256, 0, stream>>>(x, xb, (int)(SZ_X / 4));
    cast4_kernel<<<dim3((unsigned)(SZ_W / 4 / 256), 4), 256, 0, stream>>>(
        wq, wk, wv, wo, wqkvb, wqkvb + SZ_W, wqkvb + 2 * SZ_W, wob,
        (int)(SZ_W / 4));

    const int M = BATCH * SEQ;  // 8192
    gemm_bt<1><<<dim3(RQKV / 128, M / 128), 256, 0, stream>>>(
        xb, wqkvb, QKVb, M, RQKV, E_DIM);

    attn_kernel<<<dim3(SEQ / 256, NHEAD, BATCH), 256, 0, stream>>>(QKVb, attb);

    gemm_bt<0><<<dim3(E_DIM / 128, M / 128), 256, 0, stream>>>(
        attb, wob, d_out, M, E_DIM, E_DIM);
}